// Round 2
// baseline (730.953 us; speedup 1.0000x reference)
//
#include <hip/hip_runtime.h>
#include <hip/hip_bf16.h>

#define B_ 256
#define S_ 1024
#define D_ 128
#define H_ 256

typedef short short8 __attribute__((ext_vector_type(8)));
typedef float f32x4 __attribute__((ext_vector_type(4)));

// Small cross-kernel buffers live as device globals (not re-poisoned by the
// harness; prep_kernel re-initializes them every call -> same work per call).
__device__ float g_mean0[B_ * D_];            // column SUMS of x (scaled by 1/S at use)
__device__ float g_colsum1[B_ * H_];          // fp32 column sums of layer0 output
__device__ float g_colsum2[B_ * H_];
__device__ float g_colsum3[B_ * H_];
__device__ unsigned short g_Wb0[H_ * D_];     // bf16 left-half weights
__device__ unsigned short g_Wb1[H_ * H_];
__device__ unsigned short g_Wb2[H_ * H_];

__device__ __forceinline__ unsigned short f2bf(float x) {
    union { float f; unsigned u; } v; v.f = x;
    unsigned r = v.u + 0x7FFFu + ((v.u >> 16) & 1u);
    return (unsigned short)(r >> 16);
}
__device__ __forceinline__ float bf2f(unsigned short h) {
    union { float f; unsigned u; } v; v.u = ((unsigned)h) << 16;
    return v.f;
}
__device__ __forceinline__ float fast_tanh(float x) {
    float e = __builtin_amdgcn_exp2f(x * 2.885390081777927f); // 2*log2(e)
    float r = __builtin_amdgcn_rcpf(1.0f + e);
    return 1.0f - 2.0f * r;
}

// ---- prep: zero accumulators + convert W left-halves to bf16 (once) --------
__global__ __launch_bounds__(256) void prep_kernel(
    const float* __restrict__ W0, const float* __restrict__ W1,
    const float* __restrict__ W2)
{
    int i = blockIdx.x * 256 + threadIdx.x;
    if (i < 65536)            { g_colsum1[i] = 0.f; return; }
    i -= 65536;
    if (i < 65536)            { g_colsum2[i] = 0.f; return; }
    i -= 65536;
    if (i < 65536)            { g_colsum3[i] = 0.f; return; }
    i -= 65536;
    if (i < B_ * D_)          { g_mean0[i] = 0.f; return; }
    i -= B_ * D_;
    if (i < H_ * D_)          { g_Wb0[i] = f2bf(W0[(i >> 7) * 256 + (i & 127)]); return; }
    i -= H_ * D_;
    if (i < H_ * H_)          { g_Wb1[i] = f2bf(W1[(i >> 8) * 512 + (i & 255)]); return; }
    i -= H_ * H_;
    if (i < H_ * H_)          { g_Wb2[i] = f2bf(W2[(i >> 8) * 512 + (i & 255)]); return; }
}

// ---- means0: column sums of x, 4 blocks per set ---------------------------
__global__ __launch_bounds__(256) void means0_kernel(const float* __restrict__ x)
{
    const int set = blockIdx.x >> 2, part = blockIdx.x & 3;
    const int t = threadIdx.x;
    const int cg = t & 31, rg = t >> 5;              // col-group of 4, row group
    const float* xb = x + (size_t)set * S_ * D_;
    f32x4 s = (f32x4){0.f, 0.f, 0.f, 0.f};
    for (int r = part * 256 + rg; r < (part + 1) * 256; r += 8)
        s += *(const f32x4*)(xb + r * D_ + cg * 4);
    __shared__ f32x4 red[256];
    red[t] = s;
    __syncthreads();
    if (t < 32) {
        f32x4 a = red[t];
        #pragma unroll
        for (int g = 1; g < 8; ++g) a += red[g * 32 + t];
        #pragma unroll
        for (int c = 0; c < 4; ++c)
            atomicAdd(&g_mean0[set * D_ + t * 4 + c], a[c]);
    }
}

// ---- layer GEMM: grid = 256 sets x 8 row-tiles, block = 512 thr (8 waves) --
// Block tile M=128 N=256, K-chunks of 64, swizzled LDS (16B slot s of row r
// stored at slot s^(r&7); frag reads apply the same XOR -> no padding, b128 ok)
template <int LAYER>
__global__ __launch_bounds__(512, 2) void layer_kernel(
    const float* __restrict__ x, const float* __restrict__ W,
    const float* __restrict__ bias, unsigned short* __restrict__ y)
{
    constexpr int K  = (LAYER == 0) ? D_ : H_;
    constexpr int NK = K / 64;
    const int set = blockIdx.x >> 3, rt = blockIdx.x & 7;
    const int t = threadIdx.x;
    const int lane = t & 63, wave = t >> 6;
    const int l15 = lane & 15, quad = lane >> 4;
    const int mh = wave >> 2, nq = wave & 3;         // 2x4 wave grid: 64x64 tiles

    __shared__ unsigned short A_lds[128 * 64];       // 16 KB
    __shared__ unsigned short Bl_lds[256 * 64];      // 32 KB
    __shared__ float mean_lds[K];
    __shared__ float c_lds[H_];
    __shared__ float colsum_lds[H_];
    __shared__ float cpart[512];

    const unsigned short* Wb = (LAYER == 0) ? g_Wb0 : (LAYER == 1) ? g_Wb1 : g_Wb2;
    const float* msrc = (LAYER == 0) ? g_mean0 : (LAYER == 1) ? g_colsum1 : g_colsum2;
    float* csdst = (LAYER == 0) ? g_colsum1 : (LAYER == 1) ? g_colsum2 : g_colsum3;

    if (t < K) mean_lds[t] = msrc[set * K + t] * (1.f / S_);
    __syncthreads();

    // c[j] = b[j] + mean @ (W_right + (W_left - bf16(W_left))).T  (fp32)
    {
        const int j = t >> 1, h = t & 1, k0 = h * (K / 2);
        const float* wrow = W + j * 2 * K;
        float acc = 0.f;
        #pragma unroll 4
        for (int k = 0; k < K / 2; k += 4) {
            f32x4 wl = *(const f32x4*)(wrow + k0 + k);
            f32x4 wr = *(const f32x4*)(wrow + K + k0 + k);
            f32x4 m  = *(const f32x4*)(&mean_lds[k0 + k]);
            #pragma unroll
            for (int c = 0; c < 4; ++c)
                acc += m[c] * (wr[c] + (wl[c] - bf2f(f2bf(wl[c]))));
        }
        cpart[t] = acc;
    }
    __syncthreads();
    if (t < H_) {
        c_lds[t] = bias[t] + cpart[2 * t] + cpart[2 * t + 1];
        colsum_lds[t] = 0.f;
    }

    f32x4 acc[4][4];
    #pragma unroll
    for (int i = 0; i < 4; ++i)
        #pragma unroll
        for (int j = 0; j < 4; ++j) acc[i][j] = (f32x4){0.f, 0.f, 0.f, 0.f};

    const int rowA = t >> 2, qA = t & 3;             // A-stage map
    const int nB = t >> 1, hB = t & 1;               // B-stage map
    const int sw = l15 & 7;
    const int a_row = (mh * 64 + l15) * 64;
    const int b_row = (nq * 64 + l15) * 64;

    for (int kc = 0; kc < NK; ++kc) {
        __syncthreads();
        if (LAYER == 0) {
            const float* asrc = x + (size_t)(set * S_ + rt * 128 + rowA) * D_ + kc * 64 + qA * 16;
            unsigned short tmp[16];
            #pragma unroll
            for (int i = 0; i < 4; ++i) {
                f32x4 v = *(const f32x4*)(asrc + i * 4);
                #pragma unroll
                for (int c = 0; c < 4; ++c) tmp[i * 4 + c] = f2bf(v[c]);
            }
            *(uint4*)(&A_lds[rowA * 64 + ((2 * qA) ^ (rowA & 7)) * 8])     = *(const uint4*)(&tmp[0]);
            *(uint4*)(&A_lds[rowA * 64 + ((2 * qA + 1) ^ (rowA & 7)) * 8]) = *(const uint4*)(&tmp[8]);
        } else {
            const unsigned short* asrc = y + (size_t)(set * S_ + rt * 128 + rowA) * H_ + kc * 64 + qA * 16;
            uint4 v0 = ((const uint4*)asrc)[0];
            uint4 v1 = ((const uint4*)asrc)[1];
            *(uint4*)(&A_lds[rowA * 64 + ((2 * qA) ^ (rowA & 7)) * 8])     = v0;
            *(uint4*)(&A_lds[rowA * 64 + ((2 * qA + 1) ^ (rowA & 7)) * 8]) = v1;
        }
        {
            const unsigned short* bsrc = Wb + nB * K + kc * 64 + hB * 32;
            #pragma unroll
            for (int i = 0; i < 4; ++i) {
                uint4 w = ((const uint4*)bsrc)[i];
                *(uint4*)(&Bl_lds[nB * 64 + ((4 * hB + i) ^ (nB & 7)) * 8]) = w;
            }
        }
        __syncthreads();

        #pragma unroll
        for (int ks = 0; ks < 2; ++ks) {
            const int so = ((ks * 4 + quad) ^ sw) * 8;
            short8 a[4], b[4];
            #pragma unroll
            for (int ms = 0; ms < 4; ++ms) a[ms] = *(const short8*)(&A_lds[a_row + ms * 1024 + so]);
            #pragma unroll
            for (int ns = 0; ns < 4; ++ns) b[ns] = *(const short8*)(&Bl_lds[b_row + ns * 1024 + so]);
            #pragma unroll
            for (int ms = 0; ms < 4; ++ms)
                #pragma unroll
                for (int ns = 0; ns < 4; ++ns)
                    acc[ms][ns] = __builtin_amdgcn_mfma_f32_16x16x32_bf16(a[ms], b[ns], acc[ms][ns], 0, 0, 0);
        }
    }
    __syncthreads();

    // epilogue: z = acc + c; th = tanh(z); colsum += th; (L0/L1) store bf16(th)
    // C/D layout: col = lane&15, row = quad*4 + reg
    #pragma unroll
    for (int ns = 0; ns < 4; ++ns) {
        const int col = nq * 64 + ns * 16 + l15;
        const float cv = c_lds[col];
        float sn = 0.f;
        #pragma unroll
        for (int ms = 0; ms < 4; ++ms) {
            const int rowbase = rt * 128 + mh * 64 + ms * 16 + quad * 4;
            #pragma unroll
            for (int r = 0; r < 4; ++r) {
                float th = fast_tanh(acc[ms][ns][r] + cv);
                sn += th;
                if (LAYER < 2)
                    y[(size_t)(set * S_ + rowbase + r) * H_ + col] = f2bf(th);
            }
        }
        sn += __shfl_xor(sn, 16);
        sn += __shfl_xor(sn, 32);
        if (quad == 0) atomicAdd(&colsum_lds[col], sn);
    }
    __syncthreads();
    if (t < H_) atomicAdd(&csdst[set * H_ + t], colsum_lds[t]);
}

// ---- finalize: out = colsum3 / S ------------------------------------------
__global__ __launch_bounds__(256) void finalize_kernel(float* __restrict__ out)
{
    int i = blockIdx.x * 256 + threadIdx.x;
    out[i] = g_colsum3[i] * (1.f / S_);
}

extern "C" void kernel_launch(void* const* d_in, const int* in_sizes, int n_in,
                              void* d_out, int out_size, void* d_ws, size_t ws_size,
                              hipStream_t stream) {
    (void)in_sizes; (void)n_in; (void)out_size; (void)ws_size;
    const float* x  = (const float*)d_in[0];
    const float* W0 = (const float*)d_in[1];
    const float* b0 = (const float*)d_in[2];
    const float* W1 = (const float*)d_in[3];
    const float* b1 = (const float*)d_in[4];
    const float* W2 = (const float*)d_in[5];
    const float* b2 = (const float*)d_in[6];
    float* out = (float*)d_out;
    unsigned short* ws = (unsigned short*)d_ws;   // y: [256][1024][256] bf16 = 128 MiB

    // zero(4*64K floats) + Wconv(160K elems): (229376 + 163840)/256 = 1536 blocks
    prep_kernel<<<dim3(1536), dim3(256), 0, stream>>>(W0, W1, W2);
    means0_kernel<<<dim3(1024), dim3(256), 0, stream>>>(x);
    layer_kernel<0><<<dim3(2048), dim3(512), 0, stream>>>(x, W0, b0, ws);
    layer_kernel<1><<<dim3(2048), dim3(512), 0, stream>>>(x, W1, b1, ws);
    layer_kernel<2><<<dim3(2048), dim3(512), 0, stream>>>(x, W2, b2, ws);
    finalize_kernel<<<dim3(256), dim3(256), 0, stream>>>(out);
}

// Round 3
// 431.744 us; speedup vs baseline: 1.6930x; 1.6930x over previous
//
#include <hip/hip_runtime.h>
#include <hip/hip_bf16.h>

#define B_ 256
#define S_ 1024
#define D_ 128
#define H_ 256

typedef short short8 __attribute__((ext_vector_type(8)));
typedef float f32x4 __attribute__((ext_vector_type(4)));

// Cross-kernel small buffers (re-initialized every call by prep/means0/layers).
__device__ unsigned short g_Wb0[H_ * D_];   // bf16 left-half of W0
__device__ unsigned short g_Wb1[H_ * H_];
__device__ unsigned short g_Wb2[H_ * H_];
__device__ float g_mean0[B_ * D_];          // column SUMS of x
__device__ float g_colsum1[B_ * H_];        // fp32 column sums of layer outputs
__device__ float g_colsum2[B_ * H_];

__device__ __forceinline__ unsigned short f2bf(float x) {
    union { float f; unsigned u; } v; v.f = x;
    unsigned r = v.u + 0x7FFFu + ((v.u >> 16) & 1u);
    return (unsigned short)(r >> 16);
}
__device__ __forceinline__ float bf2f(unsigned short h) {
    union { float f; unsigned u; } v; v.u = ((unsigned)h) << 16;
    return v.f;
}
__device__ __forceinline__ float fast_tanh(float x) {
    float e = __builtin_amdgcn_exp2f(x * 2.885390081777927f); // 2*log2(e)
    float r = __builtin_amdgcn_rcpf(1.0f + e);
    return 1.0f - 2.0f * r;
}

// ---- prep: convert W left-halves to bf16 (no zeroing needed anywhere) ------
__global__ __launch_bounds__(256) void prep_kernel(
    const float* __restrict__ W0, const float* __restrict__ W1,
    const float* __restrict__ W2)
{
    int i = blockIdx.x * 256 + threadIdx.x;
    if (i < H_ * D_) { g_Wb0[i] = f2bf(W0[(i >> 7) * 256 + (i & 127)]); return; }
    i -= H_ * D_;
    if (i < H_ * H_) { g_Wb1[i] = f2bf(W1[(i >> 8) * 512 + (i & 255)]); return; }
    i -= H_ * H_;
    if (i < H_ * H_) { g_Wb2[i] = f2bf(W2[(i >> 8) * 512 + (i & 255)]); return; }
}

// ---- means0: one block per set, column sums of x in fp32, no atomics -------
__global__ __launch_bounds__(1024) void means0_kernel(const float* __restrict__ x)
{
    const int set = blockIdx.x, t = threadIdx.x;
    const int cg = t & 31, rg = t >> 5;               // col-group of 4, row group
    const float* xb = x + (size_t)set * S_ * D_;
    f32x4 s = (f32x4){0.f, 0.f, 0.f, 0.f};
    #pragma unroll 8
    for (int i = 0; i < 32; ++i)
        s += *(const f32x4*)(xb + (rg + i * 32) * D_ + cg * 4);
    __shared__ f32x4 red[32][32];
    red[rg][cg] = s;
    __syncthreads();
    if (t < 32) {
        f32x4 a = red[0][t];
        #pragma unroll
        for (int g = 1; g < 32; ++g) a += red[g][t];
        #pragma unroll
        for (int c = 0; c < 4; ++c) g_mean0[set * D_ + t * 4 + c] = a[c];
    }
}

// ---- layer: grid=256 (one block per set), 512 thr / 8 waves ---------------
// Wave owns 64 rows (x2 halves). A-fragments register-resident, loaded
// straight from global in MFMA layout (64B coalesced segments). W_left bf16
// fully LDS-resident, XOR-swizzled. No barriers in the compute loop.
template <int LAYER>
__global__ __launch_bounds__(512, 2) void layer_kernel(
    const float* __restrict__ x, const float* __restrict__ W,
    const float* __restrict__ bias, unsigned short* __restrict__ y,
    float* __restrict__ out)
{
    constexpr int K  = (LAYER == 0) ? D_ : H_;
    constexpr int KS = K / 32;            // 4 or 8 k-steps
    constexpr int SLOTS = K / 8;          // 16B slots per W row
    const int set = blockIdx.x;
    const int t = threadIdx.x;
    const int lane = t & 63, wave = t >> 6;
    const int l15 = lane & 15, quad = lane >> 4;

    __shared__ unsigned short W_lds[256 * K];    // 64 / 128 KB
    __shared__ float mean_lds[K];
    __shared__ float c_lds[H_];
    __shared__ float colsum_lds[H_];
    __shared__ float cpart[512];

    const unsigned short* Wb = (LAYER == 0) ? g_Wb0 : (LAYER == 1) ? g_Wb1 : g_Wb2;
    const float* msrc = (LAYER == 0) ? g_mean0 : (LAYER == 1) ? g_colsum1 : g_colsum2;

    if (t < K)   mean_lds[t] = msrc[set * K + t] * (1.f / S_);
    if (t < H_)  colsum_lds[t] = 0.f;
    __syncthreads();

    // Fill W_lds (bf16, swizzled: 16B slot s of row n stored at s^(n&7))
    {
        const int n = t >> 1, h = t & 1;
        #pragma unroll
        for (int i = 0; i < SLOTS / 2; ++i) {
            const int slot = h * (SLOTS / 2) + i;
            *(uint4*)(&W_lds[n * K + ((slot ^ (n & 7)) * 8)]) =
                *(const uint4*)(&Wb[n * K + slot * 8]);
        }
    }
    // c[j] = b[j] + mean @ (W_right + (W_left - bf16(W_left))).T  (fp32)
    {
        const int j = t >> 1, h = t & 1;
        const float* wl = W + j * 2 * K + h * (K / 2);
        const float* wr = wl + K;
        float acc = 0.f;
        #pragma unroll 4
        for (int k = 0; k < K / 2; k += 4) {
            f32x4 a = *(const f32x4*)(wl + k);
            f32x4 b = *(const f32x4*)(wr + k);
            f32x4 m = *(const f32x4*)(&mean_lds[h * (K / 2) + k]);
            #pragma unroll
            for (int c = 0; c < 4; ++c)
                acc += m[c] * (b[c] + (a[c] - bf2f(f2bf(a[c]))));
        }
        cpart[t] = acc;
    }
    __syncthreads();
    if (t < H_) c_lds[t] = bias[t] + cpart[2 * t] + cpart[2 * t + 1];
    __syncthreads();

    for (int half = 0; half < 2; ++half) {
        const int rowbase = half * 512 + wave * 64;   // within set

        // ---- A fragments: register-resident, MFMA layout ----
        short8 a[4][KS];
        if (LAYER == 0) {
            const float* xb = x + ((size_t)set * S_ + rowbase) * D_;
            #pragma unroll
            for (int mf = 0; mf < 4; ++mf)
                #pragma unroll
                for (int ks = 0; ks < KS; ++ks) {
                    const float* p = xb + (mf * 16 + l15) * D_ + ks * 32 + quad * 8;
                    f32x4 v0 = *(const f32x4*)(p);
                    f32x4 v1 = *(const f32x4*)(p + 4);
                    short8 sv;
                    #pragma unroll
                    for (int c = 0; c < 4; ++c) {
                        sv[c]     = (short)f2bf(v0[c]);
                        sv[4 + c] = (short)f2bf(v1[c]);
                    }
                    a[mf][ks] = sv;
                }
        } else {
            const unsigned short* yb = y + ((size_t)set * S_ + rowbase) * H_;
            #pragma unroll
            for (int mf = 0; mf < 4; ++mf)
                #pragma unroll
                for (int ks = 0; ks < KS; ++ks)
                    a[mf][ks] = *(const short8*)(yb + (mf * 16 + l15) * H_ + ks * 32 + quad * 8);
        }

        for (int nt = 0; nt < 8; ++nt) {              // 32-col n-tiles
            f32x4 acc[4][2];
            #pragma unroll
            for (int i = 0; i < 4; ++i) {
                acc[i][0] = (f32x4){0.f, 0.f, 0.f, 0.f};
                acc[i][1] = (f32x4){0.f, 0.f, 0.f, 0.f};
            }
            const int r0 = (nt * 32 + l15) * K;
            const int r1 = (nt * 32 + 16 + l15) * K;
            #pragma unroll
            for (int ks = 0; ks < KS; ++ks) {
                const int so = (((ks * 4 + quad) ^ (l15 & 7)) * 8);
                short8 b0 = *(const short8*)(&W_lds[r0 + so]);
                short8 b1 = *(const short8*)(&W_lds[r1 + so]);
                #pragma unroll
                for (int mf = 0; mf < 4; ++mf)
                    acc[mf][0] = __builtin_amdgcn_mfma_f32_16x16x32_bf16(a[mf][ks], b0, acc[mf][0], 0, 0, 0);
                #pragma unroll
                for (int mf = 0; mf < 4; ++mf)
                    acc[mf][1] = __builtin_amdgcn_mfma_f32_16x16x32_bf16(a[mf][ks], b1, acc[mf][1], 0, 0, 0);
            }
            // epilogue: tanh, colsum (2 shfl + 1 LDS atomic), bf16 store
            // C/D layout: col = lane&15, row = quad*4 + reg
            #pragma unroll
            for (int nf = 0; nf < 2; ++nf) {
                const int col = nt * 32 + nf * 16 + l15;
                const float cv = c_lds[col];
                float sn = 0.f;
                #pragma unroll
                for (int mf = 0; mf < 4; ++mf) {
                    #pragma unroll
                    for (int r = 0; r < 4; ++r) {
                        float th = fast_tanh(acc[mf][nf][r] + cv);
                        sn += th;
                        if (LAYER < 2)
                            y[((size_t)set * S_ + rowbase + mf * 16 + quad * 4 + r) * H_ + col] = f2bf(th);
                    }
                }
                sn += __shfl_xor(sn, 16);
                sn += __shfl_xor(sn, 32);
                if (quad == 0) atomicAdd(&colsum_lds[col], sn);
            }
        }
    }
    __syncthreads();
    if (t < H_) {
        if (LAYER == 2) out[set * H_ + t] = colsum_lds[t] * (1.f / S_);
        else if (LAYER == 1) g_colsum2[set * H_ + t] = colsum_lds[t];
        else g_colsum1[set * H_ + t] = colsum_lds[t];
    }
}

extern "C" void kernel_launch(void* const* d_in, const int* in_sizes, int n_in,
                              void* d_out, int out_size, void* d_ws, size_t ws_size,
                              hipStream_t stream) {
    (void)in_sizes; (void)n_in; (void)out_size; (void)ws_size;
    const float* x  = (const float*)d_in[0];
    const float* W0 = (const float*)d_in[1];
    const float* b0 = (const float*)d_in[2];
    const float* W1 = (const float*)d_in[3];
    const float* b1 = (const float*)d_in[4];
    const float* W2 = (const float*)d_in[5];
    const float* b2 = (const float*)d_in[6];
    float* out = (float*)d_out;
    unsigned short* ws = (unsigned short*)d_ws;   // y: [256][1024][256] bf16 = 128 MiB

    prep_kernel<<<dim3(640), dim3(256), 0, stream>>>(W0, W1, W2);
    means0_kernel<<<dim3(256), dim3(1024), 0, stream>>>(x);
    layer_kernel<0><<<dim3(256), dim3(512), 0, stream>>>(x, W0, b0, ws, out);
    layer_kernel<1><<<dim3(256), dim3(512), 0, stream>>>(x, W1, b1, ws, out);
    layer_kernel<2><<<dim3(256), dim3(512), 0, stream>>>(x, W2, b2, ws, out);
}